// Round 2
// baseline (1388.213 us; speedup 1.0000x reference)
//
#include <hip/hip_runtime.h>
#include <math.h>
#include <stddef.h>

// TransformNet fused pipeline, fp32.
// B=8, C=6, N=4096, K=20.
//
// ws layout (bytes):
//   [0)          xtp   : 8*4096*8 floats  (points padded to 8: 6 dims, xx, 0)  1,048,576
//   [1048576)    idx   : 8*4096*20 ints                                        2,621,440
//   [3670016)    h2max : 8*4096*128 floats (pre-bn2 max over k)               16,777,216
//   [20447232)   zstats: zero-initialized stats block                             42,496
//   [20489728)   tail  : bn1st(128) bn2st(256) g(8192) h4(4096) g4(4096)
//                        h5(2048) g5(2048) mat(72) bias3(24)

static constexpr float EPS_ = 1e-5f;

// ---------------- K1: transpose-pad points + squared norms ----------------
__global__ __launch_bounds__(256) void k_prep(const float* __restrict__ x,
                                              float* __restrict__ xtp)
{
    int i = blockIdx.x*256 + threadIdx.x;       // 0..32767  (b*4096+n)
    int b = i >> 12, n = i & 4095;
    const float* xb = x + (size_t)b*6*4096 + n;
    float v0 = xb[0], v1 = xb[4096], v2 = xb[2*4096];
    float v3 = xb[3*4096], v4 = xb[4*4096], v5 = xb[5*4096];
    float xx = v0*v0 + v1*v1 + v2*v2 + v3*v3 + v4*v4 + v5*v5;
    float4* o = (float4*)(xtp + (size_t)i*8);
    o[0] = make_float4(v0, v1, v2, v3);
    o[1] = make_float4(v4, v5, xx, 0.f);
}

// ---------------- K2: exact top-20 via radix bisection (2 centers/block) ----------------
// Keys live in registers (16/thread/center); LDS holds only 16-bin hists +
// small eq-index buffers. No per-winner serial extraction rounds.
__global__ __launch_bounds__(256, 6) void k_topk(const float* __restrict__ xtp,
                                                 int* __restrict__ idxout)
{
    __shared__ unsigned int hist[2][16];
    __shared__ unsigned int wcnt[2];
    __shared__ unsigned int eqcnt[2];
    __shared__ int eqbuf[2][128];

    const int t = threadIdx.x;
    const int rowbase = blockIdx.x << 1;        // 2 centers per block
    const int b = rowbase >> 12;
    const float* xb = xtp + ((size_t)b << 15);  // b*4096*8

    // centers (broadcast loads)
    float4 c0[2], c1[2];
    #pragma unroll
    for (int c = 0; c < 2; c++){
        const float4* p = (const float4*)(xtp + (size_t)(rowbase + c)*8);
        c0[c] = p[0]; c1[c] = p[1];
    }

    // distance keys: monotone map of pd (larger pd -> larger key)
    unsigned int key[2][16];
    #pragma unroll 4
    for (int i = 0; i < 16; i++){
        int m = (i << 8) | t;
        const float4* p = (const float4*)(xb + (size_t)m*8);
        float4 q0 = p[0], q1 = p[1];
        #pragma unroll
        for (int c = 0; c < 2; c++){
            float dot = c0[c].x*q0.x + c0[c].y*q0.y + c0[c].z*q0.z + c0[c].w*q0.w
                      + c1[c].x*q1.x + c1[c].y*q1.y;
            float pd = 2.f*dot - c1[c].z - q1.z;
            unsigned u = __float_as_uint(pd);
            key[c][i] = (u & 0x80000000u) ? ~u : (u | 0x80000000u);
        }
    }

    // 8 nibble rounds of bisection: find theta = 20th largest key per center
    unsigned int P[2]   = {0u, 0u};   // resolved prefix
    unsigned int cgt[2] = {0u, 0u};   // count of keys strictly above prefix region
    for (int rnd = 0; rnd < 8; rnd++){
        const int s = 28 - 4*rnd;
        if (t < 32) hist[t >> 4][t & 15] = 0u;
        __syncthreads();
        #pragma unroll
        for (int c = 0; c < 2; c++){
            unsigned long long lo = 0ull, hi = 0ull;     // 16 bins x 8-bit
            unsigned long long pref = (unsigned long long)P[c] >> (s + 4);
            #pragma unroll
            for (int i = 0; i < 16; i++){
                unsigned k = key[c][i];
                bool act = (((unsigned long long)k >> (s + 4)) == pref);
                unsigned nib = (k >> s) & 15u;
                unsigned long long inc = act ? (1ull << ((nib & 7u) << 3)) : 0ull;
                if (nib & 8u) hi += inc; else lo += inc;
            }
            // butterfly over 8-lane groups (counts <= 128, 8-bit safe)
            #pragma unroll
            for (int st = 1; st < 8; st <<= 1){
                lo += __shfl_xor(lo, st);
                hi += __shfl_xor(hi, st);
            }
            int j = (t & 7) << 1;                        // this lane's 2 bins
            unsigned long long src = (j & 8) ? hi : lo;
            unsigned v0 = (unsigned)((src >> ((j & 7) << 3)) & 0xFFull);
            unsigned v1 = (unsigned)((src >> (((j & 7) + 1) << 3)) & 0xFFull);
            if (v0) atomicAdd(&hist[c][j], v0);
            if (v1) atomicAdd(&hist[c][j + 1], v1);
        }
        __syncthreads();
        #pragma unroll
        for (int c = 0; c < 2; c++){                     // uniform scan
            unsigned cum = cgt[c];
            int chosen = 0;
            for (int v = 15; v >= 0; v--){
                unsigned hv = hist[c][v];
                if (cum + hv >= 20u){ chosen = v; break; }
                cum += hv;
            }
            P[c] |= (unsigned)chosen << s;
            cgt[c] = cum;
        }
        __syncthreads();
    }

    // collection: keys > theta are winners; keys == theta go to eq buffer
    if (t < 2){ wcnt[t] = 0u; eqcnt[t] = 0u; }
    __syncthreads();
    #pragma unroll
    for (int c = 0; c < 2; c++){
        int* out = idxout + (size_t)(rowbase + c)*20;
        unsigned theta = P[c];
        #pragma unroll
        for (int i = 0; i < 16; i++){
            unsigned k = key[c][i];
            if (k >= theta){
                int m = (i << 8) | t;
                if (k > theta){
                    unsigned pos = atomicAdd(&wcnt[c], 1u);
                    out[pos] = m;
                } else {
                    unsigned pos = atomicAdd(&eqcnt[c], 1u);
                    if (pos < 128u) eqbuf[c][pos] = m;
                }
            }
        }
    }
    __syncthreads();
    // boundary: take r = 20-cgt smallest indices among eq candidates
    const int wv = t >> 6, lane = t & 63;
    if (wv < 2){
        int c = wv;
        unsigned r  = 20u - cgt[c];
        unsigned ec = min(eqcnt[c], 128u);
        int* out = idxout + (size_t)(rowbase + c)*20;
        if (ec == r){
            for (unsigned p = lane; p < ec; p += 64) out[cgt[c] + p] = eqbuf[c][p];
        } else {
            for (unsigned rr = 0; rr < r; rr++){         // rare path
                int mv = 0x7fffffff;
                for (unsigned p = lane; p < ec; p += 64) mv = min(mv, eqbuf[c][p]);
                #pragma unroll
                for (int st = 32; st > 0; st >>= 1) mv = min(mv, __shfl_xor(mv, st));
                if (lane == 0) out[cgt[c] + rr] = mv;
                for (unsigned p = lane; p < ec; p += 64)
                    if (eqbuf[c][p] == mv) eqbuf[c][p] = 0x7fffffff;
            }
        }
    }
}

// ---------------- K3: bn1 stats (raw conv1 output sum/sumsq per channel) ----------------
__global__ __launch_bounds__(256) void k_bn1stats(const float* __restrict__ xtp,
                                                  const int* __restrict__ idxb,
                                                  const float* __restrict__ w1,
                                                  float* __restrict__ bn1sum,
                                                  float* __restrict__ bn1sq)
{
    __shared__ float fT[320*12];                // 16 rows * 20 nbrs * 12
    __shared__ float red[2][4][64];
    const int t = threadIdx.x;
    const int rowbase = blockIdx.x << 4;        // 16 rows
    const int b = rowbase >> 12;

    for (int s = t; s < 320; s += 256){
        int r = s / 20, k = s % 20;
        int grow = rowbase + r;
        int m = idxb[(size_t)grow*20 + k];
        const float4* pn = (const float4*)(xtp + (size_t)((b << 12) | m)*8);
        const float4* pc = (const float4*)(xtp + (size_t)grow*8);
        float4 n0 = pn[0], n1 = pn[1], c0 = pc[0], c1 = pc[1];
        float* f = fT + s*12;
        ((float4*)f)[0] = make_float4(n0.x-c0.x, n0.y-c0.y, n0.z-c0.z, n0.w-c0.w);
        ((float4*)f)[1] = make_float4(n1.x-c1.x, n1.y-c1.y, c0.x, c0.y);
        ((float4*)f)[2] = make_float4(c0.z, c0.w, c1.x, c1.y);
    }
    __syncthreads();
    const int o = t & 63, grp = t >> 6;
    float w[12];
    #pragma unroll
    for (int c = 0; c < 12; c++) w[c] = w1[o*12 + c];
    float sm = 0.f, sq = 0.f;
    for (int s = grp*80; s < grp*80 + 80; s++){
        const float* f = fT + s*12;
        float4 f0 = *(const float4*)(f);
        float4 fa = *(const float4*)(f + 4);
        float4 fb = *(const float4*)(f + 8);
        float h = w[0]*f0.x + w[1]*f0.y + w[2]*f0.z + w[3]*f0.w
                + w[4]*fa.x + w[5]*fa.y + w[6]*fa.z + w[7]*fa.w
                + w[8]*fb.x + w[9]*fb.y + w[10]*fb.z + w[11]*fb.w;
        sm += h; sq = fmaf(h, h, sq);
    }
    red[0][grp][o] = sm; red[1][grp][o] = sq;
    __syncthreads();
    if (t < 64){
        float a = red[0][0][t] + red[0][1][t] + red[0][2][t] + red[0][3][t];
        float c2 = red[1][0][t] + red[1][1][t] + red[1][2][t] + red[1][3][t];
        atomicAdd(bn1sum + t, a);
        atomicAdd(bn1sq + t, c2);
    }
}

// ---------------- generic BN finalize: scale/shift from sums ----------------
__global__ void k_bnfin(const float* __restrict__ sum, const float* __restrict__ sq,
                        const float* __restrict__ gamma, const float* __restrict__ beta,
                        float* __restrict__ st, int C, float invN)
{
    int o = threadIdx.x;
    if (o < C){
        float mean = sum[o]*invN;
        float var  = sq[o]*invN - mean*mean;
        float s = gamma[o]/sqrtf(var + EPS_);
        st[o] = s;
        st[C + o] = beta[o] - mean*s;
    }
}

// ---------------- K4: fused conv1+bn1+lrelu+conv2 -> max_k + bn2 stats ----------------
__global__ __launch_bounds__(256) void k_conv12(
    const float* __restrict__ xtp, const int* __restrict__ idxb,
    const float* __restrict__ w1, const float* __restrict__ w2,
    const float* __restrict__ bn1st,
    float* __restrict__ h2max, float* __restrict__ bn2sum, float* __restrict__ bn2sq)
{
    __shared__ float fT[4*20*12];       //  960
    __shared__ float f1s[4*20*64];      // 5120 (reused as 4096-float scratch)
    __shared__ float w2t[64*132];       // 8448 (w2 transposed, padded stride)
    __shared__ float w1s[64*13];        //  832
    const int t = threadIdx.x;
    const int rowbase = blockIdx.x << 2;
    const int b = rowbase >> 12;

    for (int e = t; e < 64*12; e += 256) w1s[(e/12)*13 + (e%12)] = w1[e];
    for (int e = t; e < 128*64; e += 256) w2t[(e & 63)*132 + (e >> 6)] = w2[e];
    if (t < 80){
        int r = t / 20, k = t % 20;
        int grow = rowbase + r;
        int m = idxb[(size_t)grow*20 + k];
        const float4* pn = (const float4*)(xtp + (size_t)((b << 12) | m)*8);
        const float4* pc = (const float4*)(xtp + (size_t)grow*8);
        float4 n0 = pn[0], n1 = pn[1], c0 = pc[0], c1 = pc[1];
        float* f = fT + (r*20 + k)*12;
        ((float4*)f)[0] = make_float4(n0.x-c0.x, n0.y-c0.y, n0.z-c0.z, n0.w-c0.w);
        ((float4*)f)[1] = make_float4(n1.x-c1.x, n1.y-c1.y, c0.x, c0.y);
        ((float4*)f)[2] = make_float4(c0.z, c0.w, c1.x, c1.y);
    }
    __syncthreads();
    {   // conv1 + bn1 + lrelu -> f1s
        const int j = t & 63;
        const float s1 = bn1st[j], t1 = bn1st[64 + j];
        float wr[12];
        #pragma unroll
        for (int c = 0; c < 12; c++) wr[c] = w1s[j*13 + c];
        for (int vid = t; vid < 4*20*64; vid += 256){
            const float* f = fT + (vid >> 6)*12;
            float4 f0 = *(const float4*)(f);
            float4 fa = *(const float4*)(f + 4);
            float4 fb = *(const float4*)(f + 8);
            float acc = wr[0]*f0.x + wr[1]*f0.y + wr[2]*f0.z + wr[3]*f0.w
                      + wr[4]*fa.x + wr[5]*fa.y + wr[6]*fa.z + wr[7]*fa.w
                      + wr[8]*fb.x + wr[9]*fb.y + wr[10]*fb.z + wr[11]*fb.w;
            float v = fmaf(s1, acc, t1);
            f1s[vid] = fmaxf(v, 0.2f*v);
        }
    }
    __syncthreads();
    // conv2: thread = (o-quad, k-slot); all 4 rows per thread for w2 reuse
    const int oq = t & 31, kslot = t >> 5;
    const int o0 = oq << 2;
    float mx[4][4], sm[4][4], sq[4][4];
    #pragma unroll
    for (int r = 0; r < 4; r++)
        #pragma unroll
        for (int i = 0; i < 4; i++){ mx[r][i] = -INFINITY; sm[r][i] = 0.f; sq[r][i] = 0.f; }
    for (int k = kslot; k < 20; k += 8){
        float h[4][4];
        #pragma unroll
        for (int r = 0; r < 4; r++){ h[r][0]=0.f; h[r][1]=0.f; h[r][2]=0.f; h[r][3]=0.f; }
        for (int j = 0; j < 64; j += 4){
            float wv[4][4];
            #pragma unroll
            for (int jj = 0; jj < 4; jj++)
                *(float4*)wv[jj] = *(const float4*)&w2t[(j + jj)*132 + o0];
            #pragma unroll
            for (int r = 0; r < 4; r++){
                float fv[4];
                *(float4*)fv = *(const float4*)&f1s[((r*20 + k) << 6) + j];
                #pragma unroll
                for (int jj = 0; jj < 4; jj++)
                    #pragma unroll
                    for (int oi = 0; oi < 4; oi++)
                        h[r][oi] = fmaf(fv[jj], wv[jj][oi], h[r][oi]);
            }
        }
        #pragma unroll
        for (int r = 0; r < 4; r++)
            #pragma unroll
            for (int oi = 0; oi < 4; oi++){
                mx[r][oi] = fmaxf(mx[r][oi], h[r][oi]);
                sm[r][oi] += h[r][oi];
                sq[r][oi] = fmaf(h[r][oi], h[r][oi], sq[r][oi]);
            }
    }
    __syncthreads();                    // f1s now reusable as scratch [8ks][4r][128o]
    #pragma unroll
    for (int r = 0; r < 4; r++)
        *(float4*)&f1s[((kslot << 2) + r)*128 + o0] = make_float4(mx[r][0], mx[r][1], mx[r][2], mx[r][3]);
    __syncthreads();
    for (int it = t; it < 512; it += 256){
        int r = it >> 7, o = it & 127;
        float m = f1s[r*128 + o];
        #pragma unroll
        for (int ks = 1; ks < 8; ks++) m = fmaxf(m, f1s[((ks << 2) + r)*128 + o]);
        h2max[(size_t)(rowbase + r)*128 + o] = m;
    }
    __syncthreads();
    #pragma unroll
    for (int r = 0; r < 4; r++)
        *(float4*)&f1s[((kslot << 2) + r)*128 + o0] = make_float4(sm[r][0], sm[r][1], sm[r][2], sm[r][3]);
    __syncthreads();
    if (t < 128){
        float s = 0.f;
        #pragma unroll
        for (int i = 0; i < 32; i++) s += f1s[i*128 + t];
        atomicAdd(bn2sum + t, s);
    }
    __syncthreads();
    #pragma unroll
    for (int r = 0; r < 4; r++)
        *(float4*)&f1s[((kslot << 2) + r)*128 + o0] = make_float4(sq[r][0], sq[r][1], sq[r][2], sq[r][3]);
    __syncthreads();
    if (t < 128){
        float s = 0.f;
        #pragma unroll
        for (int i = 0; i < 32; i++) s += f1s[i*128 + t];
        atomicAdd(bn2sq + t, s);
    }
}

// ---------------- K5: bn2+lrelu+conv3 -> bn3 stats + max over n ----------------
__global__ __launch_bounds__(256) void k_conv3(const float* __restrict__ h2max,
    const float* __restrict__ bn2st, const float* __restrict__ w3,
    float* __restrict__ bn3sum, float* __restrict__ bn3sq, unsigned int* __restrict__ gkey)
{
    __shared__ float f2[32*132];        // 4224 (also reused as 1024-float scratch)
    __shared__ float w3t[128*68];       // 8704
    const int t = threadIdx.x;
    const int rt = blockIdx.x >> 4;     // 1024 row tiles of 32
    const int ot = blockIdx.x & 15;     // 16 o-tiles of 64
    const int rowbase = rt << 5;
    const int obase = ot << 6;
    const int b = rowbase >> 12;

    for (int e = t; e < 32*128; e += 256){
        int r = e >> 7, c = e & 127;
        float v = h2max[(size_t)(rowbase + r)*128 + c];
        float u = fmaf(bn2st[c], v, bn2st[128 + c]);
        f2[r*132 + c] = fmaxf(u, 0.2f*u);
    }
    for (int e = t; e < 64*128; e += 256){
        int ol = e >> 7, j = e & 127;
        w3t[j*68 + ol] = w3[(size_t)(obase + ol)*128 + j];
    }
    __syncthreads();
    const int oq = t & 15, rg = t >> 4;
    const int o0 = oq << 2, r0 = rg << 1;
    float h0[4] = {0.f,0.f,0.f,0.f}, h1[4] = {0.f,0.f,0.f,0.f};
    for (int j = 0; j < 128; j += 4){
        float wv[4][4];
        #pragma unroll
        for (int jj = 0; jj < 4; jj++)
            *(float4*)wv[jj] = *(const float4*)&w3t[(j + jj)*68 + o0];
        float fa[4], fb[4];
        *(float4*)fa = *(const float4*)&f2[r0*132 + j];
        *(float4*)fb = *(const float4*)&f2[(r0 + 1)*132 + j];
        #pragma unroll
        for (int jj = 0; jj < 4; jj++)
            #pragma unroll
            for (int oi = 0; oi < 4; oi++){
                h0[oi] = fmaf(fa[jj], wv[jj][oi], h0[oi]);
                h1[oi] = fmaf(fb[jj], wv[jj][oi], h1[oi]);
            }
    }
    __syncthreads();                    // f2 reusable
    float* scratch = f2;                // [16 rg][64 o]
    *(float4*)&scratch[(rg << 6) + o0] =
        make_float4(h0[0]+h1[0], h0[1]+h1[1], h0[2]+h1[2], h0[3]+h1[3]);
    __syncthreads();
    if (t < 64){
        float s = 0.f;
        #pragma unroll
        for (int g2 = 0; g2 < 16; g2++) s += scratch[(g2 << 6) + t];
        atomicAdd(bn3sum + obase + t, s);
    }
    __syncthreads();
    *(float4*)&scratch[(rg << 6) + o0] =
        make_float4(h0[0]*h0[0]+h1[0]*h1[0], h0[1]*h0[1]+h1[1]*h1[1],
                    h0[2]*h0[2]+h1[2]*h1[2], h0[3]*h0[3]+h1[3]*h1[3]);
    __syncthreads();
    if (t < 64){
        float s = 0.f;
        #pragma unroll
        for (int g2 = 0; g2 < 16; g2++) s += scratch[(g2 << 6) + t];
        atomicAdd(bn3sq + obase + t, s);
    }
    __syncthreads();
    *(float4*)&scratch[(rg << 6) + o0] =
        make_float4(fmaxf(h0[0],h1[0]), fmaxf(h0[1],h1[1]),
                    fmaxf(h0[2],h1[2]), fmaxf(h0[3],h1[3]));
    __syncthreads();
    if (t < 64){
        float m = scratch[t];
        #pragma unroll
        for (int g2 = 1; g2 < 16; g2++) m = fmaxf(m, scratch[(g2 << 6) + t]);
        unsigned u = __float_as_uint(m);
        unsigned key = (u & 0x80000000u) ? ~u : (u | 0x80000000u);
        atomicMax(gkey + (b << 10) + obase + t, key);
    }
}

// ---------------- K5f: finalize bn3 + g = lrelu(bn3(gmax)) ----------------
__global__ void k_bn3g(const float* __restrict__ sum, const float* __restrict__ sq,
                       const unsigned int* __restrict__ gkey,
                       const float* __restrict__ gamma, const float* __restrict__ beta,
                       float* __restrict__ g)
{
    int o = blockIdx.x*256 + threadIdx.x;
    if (o < 1024){
        float mean = sum[o]*(1.f/32768.f);
        float var  = sq[o]*(1.f/32768.f) - mean*mean;
        float s = gamma[o]/sqrtf(var + EPS_);
        float tt = beta[o] - mean*s;
        for (int b = 0; b < 8; b++){
            unsigned k = gkey[(b << 10) + o];
            unsigned u = (k & 0x80000000u) ? (k & 0x7fffffffu) : ~k;
            float v = __uint_as_float(u);
            float xv = fmaf(s, v, tt);
            g[(b << 10) + o] = fmaxf(xv, 0.2f*xv);
        }
    }
}

// ---------------- FC: one wave per output ----------------
__global__ __launch_bounds__(256) void k_fc(const float* __restrict__ in,
                                            const float* __restrict__ w,
                                            float* __restrict__ out, int Kdim, int Odim)
{
    int wid = (blockIdx.x*256 + threadIdx.x) >> 6;
    int lane = threadIdx.x & 63;
    int nout = 8*Odim;
    if (wid >= nout) return;
    int b = wid / Odim, o = wid - b*Odim;
    const float* gi = in + (size_t)b*Kdim;
    const float* wr = w + (size_t)o*Kdim;
    float acc = 0.f;
    for (int c = lane; c < Kdim; c += 64) acc = fmaf(gi[c], wr[c], acc);
    #pragma unroll
    for (int s = 32; s > 0; s >>= 1) acc += __shfl_xor(acc, s);
    if (lane == 0) out[(size_t)b*Odim + o] = acc;
}

// ---------------- batch-BN (over B=8) + lrelu ----------------
__global__ void k_bnb(const float* __restrict__ h, const float* __restrict__ gamma,
                      const float* __restrict__ beta, float* __restrict__ g, int C)
{
    int o = blockIdx.x*256 + threadIdx.x;
    if (o < C){
        float s = 0.f, q = 0.f;
        for (int b = 0; b < 8; b++){ float v = h[(size_t)b*C + o]; s += v; q = fmaf(v, v, q); }
        float mean = s*0.125f;
        float var  = q*0.125f - mean*mean;
        float sc = gamma[o]/sqrtf(var + EPS_);
        float tt = beta[o] - mean*sc;
        for (int b = 0; b < 8; b++){
            float xv = fmaf(sc, h[(size_t)b*C + o], tt);
            g[(size_t)b*C + o] = fmaxf(xv, 0.2f*xv);
        }
    }
}

// ---------------- head: fc3 (-> I + 3x3) and fc4 (-> bias) ----------------
__global__ void k_head(const float* __restrict__ g5,
                       const float* __restrict__ fc3w, const float* __restrict__ fc3b,
                       const float* __restrict__ fc4w, const float* __restrict__ fc4b,
                       float* __restrict__ mat, float* __restrict__ bias3)
{
    int t = threadIdx.x;
    if (t < 96){
        int b = t / 12, j = t % 12;
        const float* gi = g5 + b*256;
        if (j < 9){
            const float* w = fc3w + j*256;
            float a = fc3b[j];
            for (int c = 0; c < 256; c++) a = fmaf(gi[c], w[c], a);
            if (j == 0 || j == 4 || j == 8) a += 1.f;
            mat[b*9 + j] = a;
        } else {
            int d = j - 9;
            const float* w = fc4w + d*256;
            float a = fc4b[d];
            for (int c = 0; c < 256; c++) a = fmaf(gi[c], w[c], a);
            bias3[b*3 + d] = a;
        }
    }
}

// ---------------- final transform: out[b,d,n] ----------------
__global__ __launch_bounds__(256) void k_out(const float* __restrict__ x,
                                             const float* __restrict__ mat,
                                             const float* __restrict__ bias3,
                                             float* __restrict__ out)
{
    int i = blockIdx.x*256 + threadIdx.x;       // 0..98303
    int n = i & 4095, bd = i >> 12;
    int b = bd / 3, d = bd - b*3;
    const float* xb = x + (size_t)b*6*4096 + n;
    const float* M = mat + b*9;
    out[i] = xb[0]*M[d] + xb[4096]*M[3 + d] + xb[2*4096]*M[6 + d] + bias3[b*3 + d];
}

// ---------------- launch ----------------
extern "C" void kernel_launch(void* const* d_in, const int* in_sizes, int n_in,
                              void* d_out, int out_size, void* d_ws, size_t ws_size,
                              hipStream_t stream)
{
    const float* x     = (const float*)d_in[0];
    const float* w1    = (const float*)d_in[1];
    const float* bn1g  = (const float*)d_in[2];
    const float* bn1b  = (const float*)d_in[3];
    const float* w2    = (const float*)d_in[4];
    const float* bn2g  = (const float*)d_in[5];
    const float* bn2b  = (const float*)d_in[6];
    const float* w3    = (const float*)d_in[7];
    const float* bn3gm = (const float*)d_in[8];
    const float* bn3bt = (const float*)d_in[9];
    const float* fc1w  = (const float*)d_in[10];
    const float* bn4g  = (const float*)d_in[11];
    const float* bn4b  = (const float*)d_in[12];
    const float* fc2w  = (const float*)d_in[13];
    const float* bn5g  = (const float*)d_in[14];
    const float* bn5b  = (const float*)d_in[15];
    const float* fc3w  = (const float*)d_in[16];
    const float* fc3b  = (const float*)d_in[17];
    const float* fc4w  = (const float*)d_in[18];
    const float* fc4b  = (const float*)d_in[19];
    float* out = (float*)d_out;

    char* ws = (char*)d_ws;
    float* xtp   = (float*)(ws);
    int*   idxb  = (int*)  (ws + 1048576);
    float* h2max = (float*)(ws + 3670016);
    float* zs    = (float*)(ws + 20447232);
    float* bn1sum = zs;            float* bn1sq = zs + 64;
    float* bn2sum = zs + 128;      float* bn2sq = zs + 256;
    float* bn3sum = zs + 384;      float* bn3sq = zs + 1408;
    unsigned int* gkey = (unsigned int*)(zs + 2432);
    float* tail  = (float*)(ws + 20489728);
    float* bn1st = tail;           // 128
    float* bn2st = tail + 128;     // 256
    float* g     = tail + 384;     // 8192
    float* h4    = tail + 8576;    // 4096
    float* g4    = tail + 12672;   // 4096
    float* h5    = tail + 16768;   // 2048
    float* g5    = tail + 18816;   // 2048
    float* mat   = tail + 20864;   // 72
    float* bias3 = tail + 20936;   // 24

    hipMemsetAsync(zs, 0, 42496, stream);

    k_prep    <<<128,   256, 0, stream>>>(x, xtp);
    k_topk    <<<16384, 256, 0, stream>>>(xtp, idxb);
    k_bn1stats<<<2048,  256, 0, stream>>>(xtp, idxb, w1, bn1sum, bn1sq);
    k_bnfin   <<<1,     128, 0, stream>>>(bn1sum, bn1sq, bn1g, bn1b, bn1st, 64, 1.f/655360.f);
    k_conv12  <<<8192,  256, 0, stream>>>(xtp, idxb, w1, w2, bn1st, h2max, bn2sum, bn2sq);
    k_bnfin   <<<1,     128, 0, stream>>>(bn2sum, bn2sq, bn2g, bn2b, bn2st, 128, 1.f/655360.f);
    k_conv3   <<<16384, 256, 0, stream>>>(h2max, bn2st, w3, bn3sum, bn3sq, gkey);
    k_bn3g    <<<4,     256, 0, stream>>>(bn3sum, bn3sq, gkey, bn3gm, bn3bt, g);
    k_fc      <<<1024,  256, 0, stream>>>(g, fc1w, h4, 1024, 512);
    k_bnb     <<<2,     256, 0, stream>>>(h4, bn4g, bn4b, g4, 512);
    k_fc      <<<512,   256, 0, stream>>>(g4, fc2w, h5, 512, 256);
    k_bnb     <<<1,     256, 0, stream>>>(h5, bn5g, bn5b, g5, 256);
    k_head    <<<1,     128, 0, stream>>>(g5, fc3w, fc3b, fc4w, fc4b, mat, bias3);
    k_out     <<<384,   256, 0, stream>>>(x, mat, bias3, out);
}

// Round 3
// 807.951 us; speedup vs baseline: 1.7182x; 1.7182x over previous
//
#include <hip/hip_runtime.h>
#include <math.h>
#include <stddef.h>

// TransformNet fused pipeline, fp32.
// B=8, C=6, N=4096, K=20.
//
// ws layout (bytes):
//   [0)          xtp   : 8*4096*8 floats  (points padded to 8: 6 dims, xx, 0)  1,048,576
//   [1048576)    idx   : 8*4096*20 ints                                        2,621,440
//   [3670016)    h2max : 8*4096*128 floats (pre-bn2 max over k)               16,777,216
//   [20447232)   zstats: zero-initialized stats block                             42,496
//   [20489728)   tail  : bn1st(128) bn2st(256) g(8192) h4(4096) g4(4096)
//                        h5(2048) g5(2048) mat(72) bias3(24)

static constexpr float EPS_ = 1e-5f;

// ---------------- K1: transpose-pad points + squared norms ----------------
__global__ __launch_bounds__(256) void k_prep(const float* __restrict__ x,
                                              float* __restrict__ xtp)
{
    int i = blockIdx.x*256 + threadIdx.x;       // 0..32767  (b*4096+n)
    int b = i >> 12, n = i & 4095;
    const float* xb = x + (size_t)b*6*4096 + n;
    float v0 = xb[0], v1 = xb[4096], v2 = xb[2*4096];
    float v3 = xb[3*4096], v4 = xb[4*4096], v5 = xb[5*4096];
    float xx = v0*v0 + v1*v1 + v2*v2 + v3*v3 + v4*v4 + v5*v5;
    float4* o = (float4*)(xtp + (size_t)i*8);
    o[0] = make_float4(v0, v1, v2, v3);
    o[1] = make_float4(v4, v5, xx, 0.f);
}

// identical fmaf chain used in both the max pass and the recompute pass so
// values are bit-identical.
__device__ __forceinline__ float pd_calc(const float4 a0, const float4 a1,
                                         const float4 q0, const float4 q1)
{
    float dot = a0.x*q0.x;
    dot = fmaf(a0.y, q0.y, dot);
    dot = fmaf(a0.z, q0.z, dot);
    dot = fmaf(a0.w, q0.w, dot);
    dot = fmaf(a1.x, q1.x, dot);
    dot = fmaf(a1.y, q1.y, dot);
    return fmaf(2.f, dot, -a1.z - q1.z);
}

// ---------------- K2: top-20 via max-prune + exact candidate select ----------------
// Phase 1: per-thread max of its 16 distances per center (registers only).
// Phase 2: wave w extracts T = ~20th largest of the 256 maxima of center w
//          (tie multi-removal only lowers T => safe: T <= true 20th element).
// Phase 3: threads with max >= T recompute their 16 dists, push >= T to LDS.
// Phase 4: wave w does exact top-20 over candidates, ties -> smallest index.
#define TK_CAP 384
__global__ __launch_bounds__(256) void k_topk(const float* __restrict__ xtp,
                                              int* __restrict__ idxout)
{
    __shared__ float maxs[4][256];
    __shared__ float candv[4][TK_CAP];
    __shared__ int   candi[4][TK_CAP];
    __shared__ float Ts[4];
    __shared__ unsigned ccnt[4];

    const int t = threadIdx.x;
    const int rowbase = blockIdx.x << 2;        // 4 centers per block
    const int b = rowbase >> 12;
    const float* xb = xtp + ((size_t)b << 15);  // b*4096*8

    float4 c0[4], c1[4];
    #pragma unroll
    for (int c = 0; c < 4; c++){
        const float4* p = (const float4*)(xtp + (size_t)(rowbase + c)*8);
        c0[c] = p[0]; c1[c] = p[1];
    }

    float mx[4] = {-INFINITY, -INFINITY, -INFINITY, -INFINITY};
    for (int i = 0; i < 16; i++){
        const float4* p = (const float4*)(xb + (size_t)((i << 8) | t)*8);
        float4 q0 = p[0], q1 = p[1];
        #pragma unroll
        for (int c = 0; c < 4; c++)
            mx[c] = fmaxf(mx[c], pd_calc(c0[c], c1[c], q0, q1));
    }
    #pragma unroll
    for (int c = 0; c < 4; c++) maxs[c][t] = mx[c];
    if (t < 4) ccnt[t] = 0u;
    __syncthreads();

    const int w = t >> 6, lane = t & 63;
    {   // phase 2: threshold for center w
        float v[4];
        #pragma unroll
        for (int j = 0; j < 4; j++) v[j] = maxs[w][(j << 6) | lane];
        float gv = -INFINITY;
        for (int r = 0; r < 20; r++){
            float bv = fmaxf(fmaxf(v[0], v[1]), fmaxf(v[2], v[3]));
            gv = bv;
            #pragma unroll
            for (int s = 1; s < 64; s <<= 1) gv = fmaxf(gv, __shfl_xor(gv, s));
            if (bv == gv){                       // remove one local instance
                if      (v[0] == gv) v[0] = -INFINITY;
                else if (v[1] == gv) v[1] = -INFINITY;
                else if (v[2] == gv) v[2] = -INFINITY;
                else                 v[3] = -INFINITY;
            }
        }
        if (lane == 0) Ts[w] = gv;
    }
    __syncthreads();

    // phase 3: candidate collection (few threads qualify per center)
    #pragma unroll
    for (int c = 0; c < 4; c++){
        if (mx[c] >= Ts[c]){
            float Tc = Ts[c];
            for (int i = 0; i < 16; i++){
                int m = (i << 8) | t;
                const float4* p = (const float4*)(xb + (size_t)m*8);
                float4 q0 = p[0], q1 = p[1];
                float pd = pd_calc(c0[c], c1[c], q0, q1);
                if (pd >= Tc){
                    unsigned pos = atomicAdd(&ccnt[c], 1u);
                    if (pos < TK_CAP){ candv[c][pos] = pd; candi[c][pos] = m; }
                }
            }
        }
    }
    __syncthreads();

    {   // phase 4: exact top-20 of center w's candidates
        int n = (int)min(ccnt[w], (unsigned)TK_CAP);
        float v[6]; int id[6];
        #pragma unroll
        for (int j = 0; j < 6; j++){
            int p = (j << 6) | lane;
            bool ok = p < n;
            v[j]  = ok ? candv[w][p] : -INFINITY;
            id[j] = ok ? candi[w][p] : 0x7fffffff;
        }
        int* out = idxout + (size_t)(rowbase + w)*20;
        for (int r = 0; r < 20; r++){
            float bv = -INFINITY; int bi = 0x7fffffff, bj = 0;
            #pragma unroll
            for (int j = 0; j < 6; j++){
                bool better = (v[j] > bv) || (v[j] == bv && id[j] < bi);
                if (better){ bv = v[j]; bi = id[j]; bj = j; }
            }
            float gv = bv; int gi = bi;
            #pragma unroll
            for (int s = 1; s < 64; s <<= 1){
                float ov = __shfl_xor(gv, s); int oi = __shfl_xor(gi, s);
                if (ov > gv || (ov == gv && oi < gi)){ gv = ov; gi = oi; }
            }
            if (lane == 0) out[r] = (gi == 0x7fffffff) ? 0 : gi;
            if (bi == gi){ v[bj] = -INFINITY; id[bj] = 0x7fffffff; }
        }
    }
}

// ---------------- K3: bn1 stats (raw conv1 output sum/sumsq per channel) ----------------
__global__ __launch_bounds__(256) void k_bn1stats(const float* __restrict__ xtp,
                                                  const int* __restrict__ idxb,
                                                  const float* __restrict__ w1,
                                                  float* __restrict__ bn1sum,
                                                  float* __restrict__ bn1sq)
{
    __shared__ float fT[320*12];                // 16 rows * 20 nbrs * 12
    __shared__ float red[2][4][64];
    const int t = threadIdx.x;
    const int rowbase = blockIdx.x << 4;        // 16 rows
    const int b = rowbase >> 12;

    for (int s = t; s < 320; s += 256){
        int r = s / 20, k = s % 20;
        int grow = rowbase + r;
        int m = idxb[(size_t)grow*20 + k];
        const float4* pn = (const float4*)(xtp + (size_t)((b << 12) | m)*8);
        const float4* pc = (const float4*)(xtp + (size_t)grow*8);
        float4 n0 = pn[0], n1 = pn[1], c0 = pc[0], c1 = pc[1];
        float* f = fT + s*12;
        ((float4*)f)[0] = make_float4(n0.x-c0.x, n0.y-c0.y, n0.z-c0.z, n0.w-c0.w);
        ((float4*)f)[1] = make_float4(n1.x-c1.x, n1.y-c1.y, c0.x, c0.y);
        ((float4*)f)[2] = make_float4(c0.z, c0.w, c1.x, c1.y);
    }
    __syncthreads();
    const int o = t & 63, grp = t >> 6;
    float w[12];
    #pragma unroll
    for (int c = 0; c < 12; c++) w[c] = w1[o*12 + c];
    float sm = 0.f, sq = 0.f;
    for (int s = grp*80; s < grp*80 + 80; s++){
        const float* f = fT + s*12;
        float4 f0 = *(const float4*)(f);
        float4 fa = *(const float4*)(f + 4);
        float4 fb = *(const float4*)(f + 8);
        float h = w[0]*f0.x + w[1]*f0.y + w[2]*f0.z + w[3]*f0.w
                + w[4]*fa.x + w[5]*fa.y + w[6]*fa.z + w[7]*fa.w
                + w[8]*fb.x + w[9]*fb.y + w[10]*fb.z + w[11]*fb.w;
        sm += h; sq = fmaf(h, h, sq);
    }
    red[0][grp][o] = sm; red[1][grp][o] = sq;
    __syncthreads();
    if (t < 64){
        float a = red[0][0][t] + red[0][1][t] + red[0][2][t] + red[0][3][t];
        float c2 = red[1][0][t] + red[1][1][t] + red[1][2][t] + red[1][3][t];
        atomicAdd(bn1sum + t, a);
        atomicAdd(bn1sq + t, c2);
    }
}

// ---------------- generic BN finalize: scale/shift from sums ----------------
__global__ void k_bnfin(const float* __restrict__ sum, const float* __restrict__ sq,
                        const float* __restrict__ gamma, const float* __restrict__ beta,
                        float* __restrict__ st, int C, float invN)
{
    int o = threadIdx.x;
    if (o < C){
        float mean = sum[o]*invN;
        float var  = sq[o]*invN - mean*mean;
        float s = gamma[o]/sqrtf(var + EPS_);
        st[o] = s;
        st[C + o] = beta[o] - mean*s;
    }
}

// ---------------- K4: fused conv1+bn1+lrelu+conv2 -> max_k + bn2 stats ----------------
__global__ __launch_bounds__(256) void k_conv12(
    const float* __restrict__ xtp, const int* __restrict__ idxb,
    const float* __restrict__ w1, const float* __restrict__ w2,
    const float* __restrict__ bn1st,
    float* __restrict__ h2max, float* __restrict__ bn2sum, float* __restrict__ bn2sq)
{
    __shared__ float fT[4*20*12];       //  960
    __shared__ float f1s[4*20*64];      // 5120 (reused as 4096-float scratch)
    __shared__ float w2t[64*132];       // 8448 (w2 transposed, padded stride)
    __shared__ float w1s[64*13];        //  832
    const int t = threadIdx.x;
    const int rowbase = blockIdx.x << 2;
    const int b = rowbase >> 12;

    for (int e = t; e < 64*12; e += 256) w1s[(e/12)*13 + (e%12)] = w1[e];
    for (int e = t; e < 128*64; e += 256) w2t[(e & 63)*132 + (e >> 6)] = w2[e];
    if (t < 80){
        int r = t / 20, k = t % 20;
        int grow = rowbase + r;
        int m = idxb[(size_t)grow*20 + k];
        const float4* pn = (const float4*)(xtp + (size_t)((b << 12) | m)*8);
        const float4* pc = (const float4*)(xtp + (size_t)grow*8);
        float4 n0 = pn[0], n1 = pn[1], c0 = pc[0], c1 = pc[1];
        float* f = fT + (r*20 + k)*12;
        ((float4*)f)[0] = make_float4(n0.x-c0.x, n0.y-c0.y, n0.z-c0.z, n0.w-c0.w);
        ((float4*)f)[1] = make_float4(n1.x-c1.x, n1.y-c1.y, c0.x, c0.y);
        ((float4*)f)[2] = make_float4(c0.z, c0.w, c1.x, c1.y);
    }
    __syncthreads();
    {   // conv1 + bn1 + lrelu -> f1s
        const int j = t & 63;
        const float s1 = bn1st[j], t1 = bn1st[64 + j];
        float wr[12];
        #pragma unroll
        for (int c = 0; c < 12; c++) wr[c] = w1s[j*13 + c];
        for (int vid = t; vid < 4*20*64; vid += 256){
            const float* f = fT + (vid >> 6)*12;
            float4 f0 = *(const float4*)(f);
            float4 fa = *(const float4*)(f + 4);
            float4 fb = *(const float4*)(f + 8);
            float acc = wr[0]*f0.x + wr[1]*f0.y + wr[2]*f0.z + wr[3]*f0.w
                      + wr[4]*fa.x + wr[5]*fa.y + wr[6]*fa.z + wr[7]*fa.w
                      + wr[8]*fb.x + wr[9]*fb.y + wr[10]*fb.z + wr[11]*fb.w;
            float v = fmaf(s1, acc, t1);
            f1s[vid] = fmaxf(v, 0.2f*v);
        }
    }
    __syncthreads();
    // conv2: thread = (o-quad, k-slot); all 4 rows per thread for w2 reuse
    const int oq = t & 31, kslot = t >> 5;
    const int o0 = oq << 2;
    float mx[4][4], sm[4][4], sq[4][4];
    #pragma unroll
    for (int r = 0; r < 4; r++)
        #pragma unroll
        for (int i = 0; i < 4; i++){ mx[r][i] = -INFINITY; sm[r][i] = 0.f; sq[r][i] = 0.f; }
    for (int k = kslot; k < 20; k += 8){
        float h[4][4];
        #pragma unroll
        for (int r = 0; r < 4; r++){ h[r][0]=0.f; h[r][1]=0.f; h[r][2]=0.f; h[r][3]=0.f; }
        for (int j = 0; j < 64; j += 4){
            float wv[4][4];
            #pragma unroll
            for (int jj = 0; jj < 4; jj++)
                *(float4*)wv[jj] = *(const float4*)&w2t[(j + jj)*132 + o0];
            #pragma unroll
            for (int r = 0; r < 4; r++){
                float fv[4];
                *(float4*)fv = *(const float4*)&f1s[((r*20 + k) << 6) + j];
                #pragma unroll
                for (int jj = 0; jj < 4; jj++)
                    #pragma unroll
                    for (int oi = 0; oi < 4; oi++)
                        h[r][oi] = fmaf(fv[jj], wv[jj][oi], h[r][oi]);
            }
        }
        #pragma unroll
        for (int r = 0; r < 4; r++)
            #pragma unroll
            for (int oi = 0; oi < 4; oi++){
                mx[r][oi] = fmaxf(mx[r][oi], h[r][oi]);
                sm[r][oi] += h[r][oi];
                sq[r][oi] = fmaf(h[r][oi], h[r][oi], sq[r][oi]);
            }
    }
    __syncthreads();                    // f1s now reusable as scratch [8ks][4r][128o]
    #pragma unroll
    for (int r = 0; r < 4; r++)
        *(float4*)&f1s[((kslot << 2) + r)*128 + o0] = make_float4(mx[r][0], mx[r][1], mx[r][2], mx[r][3]);
    __syncthreads();
    for (int it = t; it < 512; it += 256){
        int r = it >> 7, o = it & 127;
        float m = f1s[r*128 + o];
        #pragma unroll
        for (int ks = 1; ks < 8; ks++) m = fmaxf(m, f1s[((ks << 2) + r)*128 + o]);
        h2max[(size_t)(rowbase + r)*128 + o] = m;
    }
    __syncthreads();
    #pragma unroll
    for (int r = 0; r < 4; r++)
        *(float4*)&f1s[((kslot << 2) + r)*128 + o0] = make_float4(sm[r][0], sm[r][1], sm[r][2], sm[r][3]);
    __syncthreads();
    if (t < 128){
        float s = 0.f;
        #pragma unroll
        for (int i = 0; i < 32; i++) s += f1s[i*128 + t];
        atomicAdd(bn2sum + t, s);
    }
    __syncthreads();
    #pragma unroll
    for (int r = 0; r < 4; r++)
        *(float4*)&f1s[((kslot << 2) + r)*128 + o0] = make_float4(sq[r][0], sq[r][1], sq[r][2], sq[r][3]);
    __syncthreads();
    if (t < 128){
        float s = 0.f;
        #pragma unroll
        for (int i = 0; i < 32; i++) s += f1s[i*128 + t];
        atomicAdd(bn2sq + t, s);
    }
}

// ---------------- K5: bn2+lrelu+conv3 -> bn3 stats + max over n ----------------
__global__ __launch_bounds__(256) void k_conv3(const float* __restrict__ h2max,
    const float* __restrict__ bn2st, const float* __restrict__ w3,
    float* __restrict__ bn3sum, float* __restrict__ bn3sq, unsigned int* __restrict__ gkey)
{
    __shared__ float f2[32*132];        // 4224 (also reused as 1024-float scratch)
    __shared__ float w3t[128*68];       // 8704
    const int t = threadIdx.x;
    const int rt = blockIdx.x >> 4;     // 1024 row tiles of 32
    const int ot = blockIdx.x & 15;     // 16 o-tiles of 64
    const int rowbase = rt << 5;
    const int obase = ot << 6;
    const int b = rowbase >> 12;

    for (int e = t; e < 32*128; e += 256){
        int r = e >> 7, c = e & 127;
        float v = h2max[(size_t)(rowbase + r)*128 + c];
        float u = fmaf(bn2st[c], v, bn2st[128 + c]);
        f2[r*132 + c] = fmaxf(u, 0.2f*u);
    }
    for (int e = t; e < 64*128; e += 256){
        int ol = e >> 7, j = e & 127;
        w3t[j*68 + ol] = w3[(size_t)(obase + ol)*128 + j];
    }
    __syncthreads();
    const int oq = t & 15, rg = t >> 4;
    const int o0 = oq << 2, r0 = rg << 1;
    float h0[4] = {0.f,0.f,0.f,0.f}, h1[4] = {0.f,0.f,0.f,0.f};
    for (int j = 0; j < 128; j += 4){
        float wv[4][4];
        #pragma unroll
        for (int jj = 0; jj < 4; jj++)
            *(float4*)wv[jj] = *(const float4*)&w3t[(j + jj)*68 + o0];
        float fa[4], fb[4];
        *(float4*)fa = *(const float4*)&f2[r0*132 + j];
        *(float4*)fb = *(const float4*)&f2[(r0 + 1)*132 + j];
        #pragma unroll
        for (int jj = 0; jj < 4; jj++)
            #pragma unroll
            for (int oi = 0; oi < 4; oi++){
                h0[oi] = fmaf(fa[jj], wv[jj][oi], h0[oi]);
                h1[oi] = fmaf(fb[jj], wv[jj][oi], h1[oi]);
            }
    }
    __syncthreads();                    // f2 reusable
    float* scratch = f2;                // [16 rg][64 o]
    *(float4*)&scratch[(rg << 6) + o0] =
        make_float4(h0[0]+h1[0], h0[1]+h1[1], h0[2]+h1[2], h0[3]+h1[3]);
    __syncthreads();
    if (t < 64){
        float s = 0.f;
        #pragma unroll
        for (int g2 = 0; g2 < 16; g2++) s += scratch[(g2 << 6) + t];
        atomicAdd(bn3sum + obase + t, s);
    }
    __syncthreads();
    *(float4*)&scratch[(rg << 6) + o0] =
        make_float4(h0[0]*h0[0]+h1[0]*h1[0], h0[1]*h0[1]+h1[1]*h1[1],
                    h0[2]*h0[2]+h1[2]*h1[2], h0[3]*h0[3]+h1[3]*h1[3]);
    __syncthreads();
    if (t < 64){
        float s = 0.f;
        #pragma unroll
        for (int g2 = 0; g2 < 16; g2++) s += scratch[(g2 << 6) + t];
        atomicAdd(bn3sq + obase + t, s);
    }
    __syncthreads();
    *(float4*)&scratch[(rg << 6) + o0] =
        make_float4(fmaxf(h0[0],h1[0]), fmaxf(h0[1],h1[1]),
                    fmaxf(h0[2],h1[2]), fmaxf(h0[3],h1[3]));
    __syncthreads();
    if (t < 64){
        float m = scratch[t];
        #pragma unroll
        for (int g2 = 1; g2 < 16; g2++) m = fmaxf(m, scratch[(g2 << 6) + t]);
        unsigned u = __float_as_uint(m);
        unsigned key = (u & 0x80000000u) ? ~u : (u | 0x80000000u);
        atomicMax(gkey + (b << 10) + obase + t, key);
    }
}

// ---------------- K5f: finalize bn3 + g = lrelu(bn3(gmax)) ----------------
__global__ void k_bn3g(const float* __restrict__ sum, const float* __restrict__ sq,
                       const unsigned int* __restrict__ gkey,
                       const float* __restrict__ gamma, const float* __restrict__ beta,
                       float* __restrict__ g)
{
    int o = blockIdx.x*256 + threadIdx.x;
    if (o < 1024){
        float mean = sum[o]*(1.f/32768.f);
        float var  = sq[o]*(1.f/32768.f) - mean*mean;
        float s = gamma[o]/sqrtf(var + EPS_);
        float tt = beta[o] - mean*s;
        for (int b = 0; b < 8; b++){
            unsigned k = gkey[(b << 10) + o];
            unsigned u = (k & 0x80000000u) ? (k & 0x7fffffffu) : ~k;
            float v = __uint_as_float(u);
            float xv = fmaf(s, v, tt);
            g[(b << 10) + o] = fmaxf(xv, 0.2f*xv);
        }
    }
}

// ---------------- FC: one wave per output ----------------
__global__ __launch_bounds__(256) void k_fc(const float* __restrict__ in,
                                            const float* __restrict__ w,
                                            float* __restrict__ out, int Kdim, int Odim)
{
    int wid = (blockIdx.x*256 + threadIdx.x) >> 6;
    int lane = threadIdx.x & 63;
    int nout = 8*Odim;
    if (wid >= nout) return;
    int b = wid / Odim, o = wid - b*Odim;
    const float* gi = in + (size_t)b*Kdim;
    const float* wr = w + (size_t)o*Kdim;
    float acc = 0.f;
    for (int c = lane; c < Kdim; c += 64) acc = fmaf(gi[c], wr[c], acc);
    #pragma unroll
    for (int s = 32; s > 0; s >>= 1) acc += __shfl_xor(acc, s);
    if (lane == 0) out[(size_t)b*Odim + o] = acc;
}

// ---------------- batch-BN (over B=8) + lrelu ----------------
__global__ void k_bnb(const float* __restrict__ h, const float* __restrict__ gamma,
                      const float* __restrict__ beta, float* __restrict__ g, int C)
{
    int o = blockIdx.x*256 + threadIdx.x;
    if (o < C){
        float s = 0.f, q = 0.f;
        for (int b = 0; b < 8; b++){ float v = h[(size_t)b*C + o]; s += v; q = fmaf(v, v, q); }
        float mean = s*0.125f;
        float var  = q*0.125f - mean*mean;
        float sc = gamma[o]/sqrtf(var + EPS_);
        float tt = beta[o] - mean*sc;
        for (int b = 0; b < 8; b++){
            float xv = fmaf(sc, h[(size_t)b*C + o], tt);
            g[(size_t)b*C + o] = fmaxf(xv, 0.2f*xv);
        }
    }
}

// ---------------- head: fc3 (-> I + 3x3) and fc4 (-> bias) ----------------
__global__ void k_head(const float* __restrict__ g5,
                       const float* __restrict__ fc3w, const float* __restrict__ fc3b,
                       const float* __restrict__ fc4w, const float* __restrict__ fc4b,
                       float* __restrict__ mat, float* __restrict__ bias3)
{
    int t = threadIdx.x;
    if (t < 96){
        int b = t / 12, j = t % 12;
        const float* gi = g5 + b*256;
        if (j < 9){
            const float* w = fc3w + j*256;
            float a = fc3b[j];
            for (int c = 0; c < 256; c++) a = fmaf(gi[c], w[c], a);
            if (j == 0 || j == 4 || j == 8) a += 1.f;
            mat[b*9 + j] = a;
        } else {
            int d = j - 9;
            const float* w = fc4w + d*256;
            float a = fc4b[d];
            for (int c = 0; c < 256; c++) a = fmaf(gi[c], w[c], a);
            bias3[b*3 + d] = a;
        }
    }
}

// ---------------- final transform: out[b,d,n] ----------------
__global__ __launch_bounds__(256) void k_out(const float* __restrict__ x,
                                             const float* __restrict__ mat,
                                             const float* __restrict__ bias3,
                                             float* __restrict__ out)
{
    int i = blockIdx.x*256 + threadIdx.x;       // 0..98303
    int n = i & 4095, bd = i >> 12;
    int b = bd / 3, d = bd - b*3;
    const float* xb = x + (size_t)b*6*4096 + n;
    const float* M = mat + b*9;
    out[i] = xb[0]*M[d] + xb[4096]*M[3 + d] + xb[2*4096]*M[6 + d] + bias3[b*3 + d];
}

// ---------------- launch ----------------
extern "C" void kernel_launch(void* const* d_in, const int* in_sizes, int n_in,
                              void* d_out, int out_size, void* d_ws, size_t ws_size,
                              hipStream_t stream)
{
    const float* x     = (const float*)d_in[0];
    const float* w1    = (const float*)d_in[1];
    const float* bn1g  = (const float*)d_in[2];
    const float* bn1b  = (const float*)d_in[3];
    const float* w2    = (const float*)d_in[4];
    const float* bn2g  = (const float*)d_in[5];
    const float* bn2b  = (const float*)d_in[6];
    const float* w3    = (const float*)d_in[7];
    const float* bn3gm = (const float*)d_in[8];
    const float* bn3bt = (const float*)d_in[9];
    const float* fc1w  = (const float*)d_in[10];
    const float* bn4g  = (const float*)d_in[11];
    const float* bn4b  = (const float*)d_in[12];
    const float* fc2w  = (const float*)d_in[13];
    const float* bn5g  = (const float*)d_in[14];
    const float* bn5b  = (const float*)d_in[15];
    const float* fc3w  = (const float*)d_in[16];
    const float* fc3b  = (const float*)d_in[17];
    const float* fc4w  = (const float*)d_in[18];
    const float* fc4b  = (const float*)d_in[19];
    float* out = (float*)d_out;

    char* ws = (char*)d_ws;
    float* xtp   = (float*)(ws);
    int*   idxb  = (int*)  (ws + 1048576);
    float* h2max = (float*)(ws + 3670016);
    float* zs    = (float*)(ws + 20447232);
    float* bn1sum = zs;            float* bn1sq = zs + 64;
    float* bn2sum = zs + 128;      float* bn2sq = zs + 256;
    float* bn3sum = zs + 384;      float* bn3sq = zs + 1408;
    unsigned int* gkey = (unsigned int*)(zs + 2432);
    float* tail  = (float*)(ws + 20489728);
    float* bn1st = tail;           // 128
    float* bn2st = tail + 128;     // 256
    float* g     = tail + 384;     // 8192
    float* h4    = tail + 8576;    // 4096
    float* g4    = tail + 12672;   // 4096
    float* h5    = tail + 16768;   // 2048
    float* g5    = tail + 18816;   // 2048
    float* mat   = tail + 20864;   // 72
    float* bias3 = tail + 20936;   // 24

    hipMemsetAsync(zs, 0, 42496, stream);

    k_prep    <<<128,   256, 0, stream>>>(x, xtp);
    k_topk    <<<8192,  256, 0, stream>>>(xtp, idxb);
    k_bn1stats<<<2048,  256, 0, stream>>>(xtp, idxb, w1, bn1sum, bn1sq);
    k_bnfin   <<<1,     128, 0, stream>>>(bn1sum, bn1sq, bn1g, bn1b, bn1st, 64, 1.f/655360.f);
    k_conv12  <<<8192,  256, 0, stream>>>(xtp, idxb, w1, w2, bn1st, h2max, bn2sum, bn2sq);
    k_bnfin   <<<1,     128, 0, stream>>>(bn2sum, bn2sq, bn2g, bn2b, bn2st, 128, 1.f/655360.f);
    k_conv3   <<<16384, 256, 0, stream>>>(h2max, bn2st, w3, bn3sum, bn3sq, gkey);
    k_bn3g    <<<4,     256, 0, stream>>>(bn3sum, bn3sq, gkey, bn3gm, bn3bt, g);
    k_fc      <<<1024,  256, 0, stream>>>(g, fc1w, h4, 1024, 512);
    k_bnb     <<<2,     256, 0, stream>>>(h4, bn4g, bn4b, g4, 512);
    k_fc      <<<512,   256, 0, stream>>>(g4, fc2w, h5, 512, 256);
    k_bnb     <<<1,     256, 0, stream>>>(h5, bn5g, bn5b, g5, 256);
    k_head    <<<1,     128, 0, stream>>>(g5, fc3w, fc3b, fc4w, fc4b, mat, bias3);
    k_out     <<<384,   256, 0, stream>>>(x, mat, bias3, out);
}